// Round 8
// baseline (659.901 us; speedup 1.0000x reference)
//
#include <hip/hip_runtime.h>
#include <hip/hip_bf16.h>
#include <math.h>

typedef __attribute__((ext_vector_type(8))) short bf16x8;
typedef __attribute__((ext_vector_type(16))) float f32x16;

#define NROWS 16384
#define DIM 128
#define NB 128                   // 128x128 tiles per dim
#define TRI (NB * (NB + 1) / 2)  // 8256 triangular blocks
#define TOTAL_BLOCKS (2 * TRI + NB * NB)  // 32896, divisible by 8

// Ab entries are pre-scaled by sqrt(2/ln2) so that the bf16 Gram dot equals
// x * 2/ln2, i.e. exp(x/tau) = exp2(dot) with no epilogue multiply.
#define OP_SCALE 1.69864360057604f
// exp(1/tau) = exp(2): the refl diagonal (an.an == 1 exactly)
#define E2 7.38905609893065f

// raw v_exp_f32 when available (args provably in [-3,3]; no guards needed)
#if __has_builtin(__builtin_amdgcn_exp2f)
#define EXP2(x) __builtin_amdgcn_exp2f(x)
#else
#define EXP2(x) __expf((x) * 0.6931471805599453f)
#endif

// ---------------------------------------------------------------------------
// Projection: h = elu(z@W1+b1)@W2+b2 ; A = h/max(||h||,eps). fp32 throughout.
// Emits fp32 copy (for exact diag) and pre-scaled bf16 copy (for MFMA).
// Both z1 and z2 in ONE launch: blocks [0,1024) -> z1/Af/Ab,
// [1024,2048) -> z2/Bf/Bb. Block = 128 threads, 16 rows per block.
// ---------------------------------------------------------------------------
__global__ __launch_bounds__(128) void proj_kernel(
    const float* __restrict__ z1, const float* __restrict__ z2,
    const float* __restrict__ W1, const float* __restrict__ b1,
    const float* __restrict__ W2, const float* __restrict__ b2,
    float* __restrict__ Af, float* __restrict__ Bf,
    __hip_bfloat16* __restrict__ Ab, __hip_bfloat16* __restrict__ Bb)
{
    const int ROWS = 16;
    const int HALF = NROWS / ROWS;         // 1024 blocks per input
    __shared__ float zs[ROWS][DIM];
    __shared__ float es[ROWS][DIM];
    __shared__ float wavesum[2][ROWS];
    __shared__ float scale[ROWS];

    const int tid = threadIdx.x;           // 0..127 (owns one output column)
    const bool second = blockIdx.x >= HALF;
    const float* z = second ? z2 : z1;
    float* Xf = second ? Bf : Af;
    __hip_bfloat16* Xb = second ? Bb : Ab;
    const int row0 = (second ? blockIdx.x - HALF : blockIdx.x) * ROWS;

    #pragma unroll
    for (int r = 0; r < ROWS; ++r)
        zs[r][tid] = z[(row0 + r) * DIM + tid];
    __syncthreads();

    float acc[ROWS];
    #pragma unroll
    for (int r = 0; r < ROWS; ++r) acc[r] = 0.f;
    for (int k = 0; k < DIM; ++k) {
        float w = W1[k * DIM + tid];
        #pragma unroll
        for (int r = 0; r < ROWS; ++r) acc[r] = fmaf(zs[r][k], w, acc[r]);
    }
    float bb1 = b1[tid];
    #pragma unroll
    for (int r = 0; r < ROWS; ++r) {
        float t = acc[r] + bb1;
        es[r][tid] = t > 0.f ? t : expm1f(t);   // elu, alpha=1
    }
    __syncthreads();

    #pragma unroll
    for (int r = 0; r < ROWS; ++r) acc[r] = 0.f;
    for (int h = 0; h < DIM; ++h) {
        float w = W2[h * DIM + tid];
        #pragma unroll
        for (int r = 0; r < ROWS; ++r) acc[r] = fmaf(es[r][h], w, acc[r]);
    }
    float bb2 = b2[tid];
    #pragma unroll
    for (int r = 0; r < ROWS; ++r) acc[r] += bb2;

    // per-row L2 norms: shuffle-reduce within each of the 2 waves, combine in LDS
    const int wave = tid >> 6, lane = tid & 63;
    #pragma unroll
    for (int r = 0; r < ROWS; ++r) {
        float s = acc[r] * acc[r];
        #pragma unroll
        for (int off = 32; off; off >>= 1) s += __shfl_xor(s, off);
        if (lane == 0) wavesum[wave][r] = s;
    }
    __syncthreads();
    if (tid < ROWS) {
        float n = sqrtf(wavesum[0][tid] + wavesum[1][tid]);
        scale[tid] = 1.f / fmaxf(n, 1e-12f);
    }
    __syncthreads();

    #pragma unroll
    for (int r = 0; r < ROWS; ++r) {
        float a = acc[r] * scale[r];
        Xf[(row0 + r) * DIM + tid] = a;
        Xb[(row0 + r) * DIM + tid] = __float2bfloat16(a * OP_SCALE);
    }
}

// ---------------------------------------------------------------------------
// Select-exchange fold: combine two per-lane partial sets a,b over xor-pairs d.
// Result: lanes with (lane&d)==0 carry a[l]+a[l^d]; ==1 carry b[l]+b[l^d].
// ---------------------------------------------------------------------------
__device__ __forceinline__ float fold2(float a, float b, int d, int lane) {
    float x = (lane & d) ? b : a;
    float y = (lane & d) ? a : b;
    return x + __shfl_xor(y, d);
}

// ---------------------------------------------------------------------------
// Fused pairwise exp-Gram sums, single 1D grid covering all three products:
//   region 0: AA (symmetric, triangular blocks bx<=by), rowS = S_AA
//   region 1: AB (full grid), rowS = S_AB, colS = S_BA
//   region 2: BB (symmetric, triangular), rowS = S_BB
// Symmetric regions: off-diagonal blocks scatter their tile column sums as
// the transposed block's row sums (exp Gram matrix is symmetric); diagonal
// blocks (bx==by) skip the column epilogue entirely.
// 256 threads = 4 waves (2x2 of 64x64), 128x128 tile, K=128 single pass.
// Inner product: mfma_f32_32x32x16_bf16, 2x2 of 32x32 per wave, 8 K-steps.
// A/B frag: row/col = lane&31, k = kk*16 + (lane>>5)*8 + e. C/D: col=lane&31,
// row = (reg&3)+8*(reg>>2)+4*(lane>>5)  [m74/m101-verified].
// Row sums use a 4-step multi-value butterfly fold (16 regs -> 1 reg holding
// all 16 sums indexed by lane&15) + shfl_xor(16), then ONE 32-lane
// conflict-free LDS atomic per m-subtile.
// ---------------------------------------------------------------------------
__global__ __launch_bounds__(256) void pairsum_all_kernel(
    const short* __restrict__ Ab, const short* __restrict__ Bb,
    float* __restrict__ S_AA, float* __restrict__ S_AB,
    float* __restrict__ S_BA, float* __restrict__ S_BB)
{
    // bijective XCD swizzle: 32896 = 8 * 4112
    const int bid0 = blockIdx.x;
    const int t0 = (bid0 & 7) * (TOTAL_BLOCKS / 8) + (bid0 >> 3);

    const short* A;
    const short* B;
    float* rowS;
    float* colS = nullptr;
    int bx, by, sym;

    if (t0 < TRI) {                       // AA triangular
        int t = t0;
        by = (int)((sqrtf(8.0f * t + 1.0f) - 1.0f) * 0.5f);
        while ((by + 1) * (by + 2) / 2 <= t) ++by;
        while (by * (by + 1) / 2 > t) --by;
        bx = t - by * (by + 1) / 2;
        A = Ab; B = Ab; rowS = S_AA; sym = 1;
    } else if (t0 < TRI + NB * NB) {      // AB full
        int t = t0 - TRI;
        by = t / NB; bx = t % NB;
        A = Ab; B = Bb; rowS = S_AB; colS = S_BA; sym = 0;
    } else {                              // BB triangular
        int t = t0 - TRI - NB * NB;
        by = (int)((sqrtf(8.0f * t + 1.0f) - 1.0f) * 0.5f);
        while ((by + 1) * (by + 2) / 2 <= t) ++by;
        while (by * (by + 1) / 2 > t) --by;
        bx = t - by * (by + 1) / 2;
        A = Bb; B = Bb; rowS = S_BB; sym = 1;
    }
    const bool needCols = !sym || (bx != by);

    __shared__ float rbuf[128];
    __shared__ float cbuf[128];
    const int tid = threadIdx.x;
    if (tid < 128) { rbuf[tid] = 0.f; cbuf[tid] = 0.f; }
    __syncthreads();

    const int wid = tid >> 6, lane = tid & 63;
    const int wr = wid >> 1, wc = wid & 1;
    const int rowBase0 = by * 128;
    const int colBase0 = bx * 128;
    const int rowBase = rowBase0 + wr * 64;
    const int colBase = colBase0 + wc * 64;
    const int lr32 = lane & 31;   // row (A) / col (B) within 32-fragment
    const int kh = lane >> 5;     // k-half (8 contiguous k each)

    f32x16 acc[2][2];
    #pragma unroll
    for (int m = 0; m < 2; ++m)
        #pragma unroll
        for (int n = 0; n < 2; ++n)
            #pragma unroll
            for (int r = 0; r < 16; ++r) acc[m][n][r] = 0.f;

    #pragma unroll
    for (int kk = 0; kk < 8; ++kk) {
        const int koff = kk * 16 + kh * 8;
        bf16x8 a[2], b[2];
        #pragma unroll
        for (int m = 0; m < 2; ++m)
            a[m] = *(const bf16x8*)(A + (size_t)(rowBase + m * 32 + lr32) * DIM + koff);
        #pragma unroll
        for (int n = 0; n < 2; ++n)
            b[n] = *(const bf16x8*)(B + (size_t)(colBase + n * 32 + lr32) * DIM + koff);
        #pragma unroll
        for (int m = 0; m < 2; ++m)
            #pragma unroll
            for (int n = 0; n < 2; ++n)
                acc[m][n] = __builtin_amdgcn_mfma_f32_32x32x16_bf16(a[m], b[n], acc[m][n], 0, 0, 0);
    }

    // exp + reductions. acc = x*2/ln2 (operands pre-scaled): bare v_exp_f32.
    float colpart[2] = {0.f, 0.f};
    #pragma unroll
    for (int m = 0; m < 2; ++m) {
        float rowpart[16];
        #pragma unroll
        for (int r = 0; r < 16; ++r) rowpart[r] = 0.f;
        #pragma unroll
        for (int n = 0; n < 2; ++n) {
            #pragma unroll
            for (int r = 0; r < 16; ++r) {
                float e = EXP2(acc[m][n][r]);
                rowpart[r] += e;
                colpart[n] += e;
            }
        }
        // multi-value fold: 16 regs over 32 lanes -> 1 reg (value = lane&15)
        float f[8], g[4], h[2], t;
        #pragma unroll
        for (int j = 0; j < 8; ++j) f[j] = fold2(rowpart[2*j], rowpart[2*j+1], 1, lane);
        #pragma unroll
        for (int j = 0; j < 4; ++j) g[j] = fold2(f[2*j], f[2*j+1], 2, lane);
        #pragma unroll
        for (int j = 0; j < 2; ++j) h[j] = fold2(g[2*j], g[2*j+1], 4, lane);
        t = fold2(h[0], h[1], 8, lane);
        t += __shfl_xor(t, 16);
        // lane l holds the full 32-col sum of reg r=l&15, i.e. row
        // (r&3)+8*((r>>2)&3)+4*kh of sub-tile m (duplicated at l^16).
        if ((lane & 16) == 0)
            atomicAdd(&rbuf[wr * 64 + m * 32 + (lane & 3) + 8 * ((lane >> 2) & 3) + 4 * kh], t);
    }
    if (needCols) {
        // col sums: lane l and l^32 hold the two row-halves of the same col
        #pragma unroll
        for (int n = 0; n < 2; ++n) {
            float s = colpart[n];
            s += __shfl_xor(s, 32);
            if (lane < 32) atomicAdd(&cbuf[wc * 64 + n * 32 + lr32], s);
        }
    }
    __syncthreads();

    if (tid < 128) {
        atomicAdd(rowS + rowBase0 + tid, rbuf[tid]);
        if (sym) {
            if (bx != by) atomicAdd(rowS + colBase0 + tid, cbuf[tid]);
        } else {
            atomicAdd(colS + colBase0 + tid, cbuf[tid]);
        }
    }
}

// ---------------------------------------------------------------------------
// fp32 diagonal of the between matrix: dAB[i] = A_i . B_i  (unit vectors).
// (an.an == bn.bn == 1, so the refl diagonals are the constant e^2.)
// one wave per row, 4 rows per block.
// ---------------------------------------------------------------------------
__global__ __launch_bounds__(256) void diag_kernel(
    const float* __restrict__ Af, const float* __restrict__ Bf,
    float* __restrict__ dAB)
{
    const int wid = threadIdx.x >> 6, lane = threadIdx.x & 63;
    const int i = blockIdx.x * 4 + wid;
    float a0 = Af[(size_t)i * DIM + lane],      a1 = Af[(size_t)i * DIM + 64 + lane];
    float b0 = Bf[(size_t)i * DIM + lane],      b1 = Bf[(size_t)i * DIM + 64 + lane];
    float ab = a0 * b0 + a1 * b1;
    #pragma unroll
    for (int off = 32; off; off >>= 1) ab += __shfl_xor(ab, off);
    if (lane == 0) dAB[i] = ab;
}

// ---------------------------------------------------------------------------
// Final loss: mean over i of 0.5*(log den1 + log den2) - dAB/tau
//   den1 = S_AA[i] + S_AB[i] - e^2 ; den2 = S_BB[i] + S_BA[i] - e^2
// ---------------------------------------------------------------------------
__global__ __launch_bounds__(256) void loss_kernel(
    const float* __restrict__ sAA, const float* __restrict__ sAB,
    const float* __restrict__ sBA, const float* __restrict__ sBB,
    const float* __restrict__ dAB, float* __restrict__ out)
{
    __shared__ double part[256];
    double s = 0.0;
    for (int i = threadIdx.x; i < NROWS; i += 256) {
        float den1 = sAA[i] + sAB[i] - E2;
        float den2 = sBB[i] + sBA[i] - E2;
        s += 0.5 * ((double)logf(den1) + (double)logf(den2)) - (double)dAB[i] * 2.0;
    }
    part[threadIdx.x] = s;
    __syncthreads();
    for (int off = 128; off; off >>= 1) {
        if (threadIdx.x < off) part[threadIdx.x] += part[threadIdx.x + off];
        __syncthreads();
    }
    if (threadIdx.x == 0) out[0] = (float)(part[0] / NROWS);
}

// ---------------------------------------------------------------------------
extern "C" void kernel_launch(void* const* d_in, const int* in_sizes, int n_in,
                              void* d_out, int out_size, void* d_ws, size_t ws_size,
                              hipStream_t stream) {
    const float* z1 = (const float*)d_in[0];
    const float* z2 = (const float*)d_in[1];
    const float* W1 = (const float*)d_in[2];
    const float* b1 = (const float*)d_in[3];
    const float* W2 = (const float*)d_in[4];
    const float* b2 = (const float*)d_in[5];
    float* out = (float*)d_out;

    char* w = (char*)d_ws;
    float* Af = (float*)w;                 w += (size_t)NROWS * DIM * sizeof(float);
    float* Bf = (float*)w;                 w += (size_t)NROWS * DIM * sizeof(float);
    __hip_bfloat16* Ab = (__hip_bfloat16*)w; w += (size_t)NROWS * DIM * sizeof(__hip_bfloat16);
    __hip_bfloat16* Bb = (__hip_bfloat16*)w; w += (size_t)NROWS * DIM * sizeof(__hip_bfloat16);
    float* S_AA = (float*)w;               w += NROWS * sizeof(float);
    float* S_AB = (float*)w;               w += NROWS * sizeof(float);
    float* S_BA = (float*)w;               w += NROWS * sizeof(float);
    float* S_BB = (float*)w;               w += NROWS * sizeof(float);
    float* dAB  = (float*)w;               w += NROWS * sizeof(float);

    // zero the four accumulator arrays (contiguous)
    hipMemsetAsync(S_AA, 0, 4 * NROWS * sizeof(float), stream);

    proj_kernel<<<2 * (NROWS / 16), 128, 0, stream>>>(
        z1, z2, W1, b1, W2, b2, Af, Bf, Ab, Bb);

    pairsum_all_kernel<<<TOTAL_BLOCKS, 256, 0, stream>>>(
        (const short*)Ab, (const short*)Bb, S_AA, S_AB, S_BA, S_BB);

    diag_kernel<<<NROWS / 4, 256, 0, stream>>>(Af, Bf, dAB);
    loss_kernel<<<1, 256, 0, stream>>>(S_AA, S_AB, S_BA, S_BB, dAB, out);
}

// Round 10
// 493.741 us; speedup vs baseline: 1.3365x; 1.3365x over previous
//
#include <hip/hip_runtime.h>
#include <hip/hip_bf16.h>
#include <math.h>

typedef __attribute__((ext_vector_type(8))) short bf16x8;
typedef __attribute__((ext_vector_type(16))) float f32x16;

#define NROWS 16384
#define DIM 128
#define NB 128                   // 128x128 tiles per dim
#define TRI (NB * (NB + 1) / 2)  // 8256 triangular blocks
#define TOTAL_BLOCKS (2 * TRI + NB * NB)  // 32896, divisible by 8

// Ab entries are pre-scaled by sqrt(2/ln2) so that the bf16 Gram dot equals
// x * 2/ln2, i.e. exp(x/tau) = exp2(dot) with no epilogue multiply.
#define OP_SCALE 1.69864360057604f
// exp(1/tau) = exp(2): the refl diagonal (an.an == 1 exactly)
#define E2 7.38905609893065f

// raw v_exp_f32 when available (args provably in [-3,3]; no guards needed)
#if __has_builtin(__builtin_amdgcn_exp2f)
#define EXP2(x) __builtin_amdgcn_exp2f(x)
#else
#define EXP2(x) __expf((x) * 0.6931471805599453f)
#endif

// ---------------------------------------------------------------------------
// Projection: h = elu(z@W1+b1)@W2+b2 ; A = h/max(||h||,eps). fp32 throughout.
// Emits fp32 copy (for exact diag) and pre-scaled bf16 copy (for MFMA).
// Both z1 and z2 in ONE launch. Block = 128 threads, 16 rows per block.
// ---------------------------------------------------------------------------
__global__ __launch_bounds__(128) void proj_kernel(
    const float* __restrict__ z1, const float* __restrict__ z2,
    const float* __restrict__ W1, const float* __restrict__ b1,
    const float* __restrict__ W2, const float* __restrict__ b2,
    float* __restrict__ Af, float* __restrict__ Bf,
    __hip_bfloat16* __restrict__ Ab, __hip_bfloat16* __restrict__ Bb)
{
    const int ROWS = 16;
    const int HALF = NROWS / ROWS;         // 1024 blocks per input
    __shared__ float zs[ROWS][DIM];
    __shared__ float es[ROWS][DIM];
    __shared__ float wavesum[2][ROWS];
    __shared__ float scale[ROWS];

    const int tid = threadIdx.x;           // 0..127 (owns one output column)
    const bool second = blockIdx.x >= HALF;
    const float* z = second ? z2 : z1;
    float* Xf = second ? Bf : Af;
    __hip_bfloat16* Xb = second ? Bb : Ab;
    const int row0 = (second ? blockIdx.x - HALF : blockIdx.x) * ROWS;

    #pragma unroll
    for (int r = 0; r < ROWS; ++r)
        zs[r][tid] = z[(row0 + r) * DIM + tid];
    __syncthreads();

    float acc[ROWS];
    #pragma unroll
    for (int r = 0; r < ROWS; ++r) acc[r] = 0.f;
    for (int k = 0; k < DIM; ++k) {
        float w = W1[k * DIM + tid];
        #pragma unroll
        for (int r = 0; r < ROWS; ++r) acc[r] = fmaf(zs[r][k], w, acc[r]);
    }
    float bb1 = b1[tid];
    #pragma unroll
    for (int r = 0; r < ROWS; ++r) {
        float t = acc[r] + bb1;
        es[r][tid] = t > 0.f ? t : expm1f(t);   // elu, alpha=1
    }
    __syncthreads();

    #pragma unroll
    for (int r = 0; r < ROWS; ++r) acc[r] = 0.f;
    for (int h = 0; h < DIM; ++h) {
        float w = W2[h * DIM + tid];
        #pragma unroll
        for (int r = 0; r < ROWS; ++r) acc[r] = fmaf(es[r][h], w, acc[r]);
    }
    float bb2 = b2[tid];
    #pragma unroll
    for (int r = 0; r < ROWS; ++r) acc[r] += bb2;

    // per-row L2 norms: shuffle-reduce within each of the 2 waves, combine in LDS
    const int wave = tid >> 6, lane = tid & 63;
    #pragma unroll
    for (int r = 0; r < ROWS; ++r) {
        float s = acc[r] * acc[r];
        #pragma unroll
        for (int off = 32; off; off >>= 1) s += __shfl_xor(s, off);
        if (lane == 0) wavesum[wave][r] = s;
    }
    __syncthreads();
    if (tid < ROWS) {
        float n = sqrtf(wavesum[0][tid] + wavesum[1][tid]);
        scale[tid] = 1.f / fmaxf(n, 1e-12f);
    }
    __syncthreads();

    #pragma unroll
    for (int r = 0; r < ROWS; ++r) {
        float a = acc[r] * scale[r];
        Xf[(row0 + r) * DIM + tid] = a;
        Xb[(row0 + r) * DIM + tid] = __float2bfloat16(a * OP_SCALE);
    }
}

// ---------------------------------------------------------------------------
// Select-exchange fold: combine two per-lane partial sets a,b over xor-pairs d.
// ---------------------------------------------------------------------------
__device__ __forceinline__ float fold2(float a, float b, int d, int lane) {
    float x = (lane & d) ? b : a;
    float y = (lane & d) ? a : b;
    return x + __shfl_xor(y, d);
}

// ---------------------------------------------------------------------------
// Fused pairwise exp-Gram sums, single 1D grid covering all three products:
//   region 0: AA (symmetric, triangular blocks bx<=by), rowS = S_AA
//   region 1: AB (full grid, L2-supertiled 8by x 16bx), rowS=S_AB, colS=S_BA
//   region 2: BB (symmetric, triangular), rowS = S_BB
// 256 threads = 4 waves (2x2 of 64x64), 128x128 tile, K=128 single pass.
//
// Data path: A/B tiles reg-staged to LDS (64 KB/block, fully-coalesced
// 32KB slab loads), G4 XOR swizzle byte^=((row&7)<<4) on BOTH ds_write and
// ds_read sides (involution) -> bank-touch distribution at the structural
// floor (8/bank for wave64 b128; unswizzled would be 64/4 banks).
// Inner product: mfma_f32_32x32x16_bf16, 2x2 of 32x32 per wave, 8 K-steps.
// C/D: col=lane&31, row=(reg&3)+8*(reg>>2)+4*(lane>>5) [m74/m101-verified].
// Row sums: 4-step multi-value butterfly fold + shfl_xor(16) + one 32-lane
// conflict-free LDS atomic per m-subtile.
// ---------------------------------------------------------------------------
__global__ __launch_bounds__(256) void pairsum_all_kernel(
    const short* __restrict__ Ab, const short* __restrict__ Bb,
    float* __restrict__ S_AA, float* __restrict__ S_AB,
    float* __restrict__ S_BA, float* __restrict__ S_BB)
{
    // bijective XCD swizzle: 32896 = 8 * 4112
    const int bid0 = blockIdx.x;
    const int t0 = (bid0 & 7) * (TOTAL_BLOCKS / 8) + (bid0 >> 3);

    const short* A;
    const short* B;
    float* rowS;
    float* colS = nullptr;
    int bx, by, sym;

    if (t0 < TRI) {                       // AA triangular
        int t = t0;
        by = (int)((sqrtf(8.0f * t + 1.0f) - 1.0f) * 0.5f);
        while ((by + 1) * (by + 2) / 2 <= t) ++by;
        while (by * (by + 1) / 2 > t) --by;
        bx = t - by * (by + 1) / 2;
        A = Ab; B = Ab; rowS = S_AA; sym = 1;
    } else if (t0 < TRI + NB * NB) {      // AB full, supertiled for L2
        int t = t0 - TRI;
        // supertile: 8 by-panels x 16 bx-panels = 768 KB working set << 4MB L2
        int st = t >> 7, win = t & 127;
        int stx = st & 7, sty = st >> 3;
        bx = stx * 16 + (win & 15);
        by = sty * 8 + (win >> 4);
        A = Ab; B = Bb; rowS = S_AB; colS = S_BA; sym = 0;
    } else {                              // BB triangular
        int t = t0 - TRI - NB * NB;
        by = (int)((sqrtf(8.0f * t + 1.0f) - 1.0f) * 0.5f);
        while ((by + 1) * (by + 2) / 2 <= t) ++by;
        while (by * (by + 1) / 2 > t) --by;
        bx = t - by * (by + 1) / 2;
        A = Bb; B = Bb; rowS = S_BB; sym = 1;
    }
    const bool needCols = !sym || (bx != by);

    __shared__ short lA[NB * DIM];        // 32 KB, swizzled rows of 256B
    __shared__ short lB[NB * DIM];        // 32 KB
    __shared__ float rbuf[128];
    __shared__ float cbuf[128];
    const int tid = threadIdx.x;
    if (tid < 128) { rbuf[tid] = 0.f; cbuf[tid] = 0.f; }

    // ---- stage: 32KB contiguous slab per operand, 8x 16B units per thread
    {
        const short* gA = A + (size_t)by * 128 * DIM;
        const short* gB = B + (size_t)bx * 128 * DIM;
        bf16x8 av[8], bv[8];
        #pragma unroll
        for (int i = 0; i < 8; ++i) {
            const int unit = i * 256 + tid;        // 16B unit index 0..2047
            av[i] = *(const bf16x8*)(gA + unit * 8);
            bv[i] = *(const bf16x8*)(gB + unit * 8);
        }
        #pragma unroll
        for (int i = 0; i < 8; ++i) {
            const int unit = i * 256 + tid;
            const int row = unit >> 4;             // local row 0..127
            const int dst = row * 256 + (((unit & 15) * 16) ^ ((row & 7) << 4));
            *(bf16x8*)((char*)lA + dst) = av[i];
            *(bf16x8*)((char*)lB + dst) = bv[i];
        }
    }
    __syncthreads();

    const int wid = tid >> 6, lane = tid & 63;
    const int wr = wid >> 1, wc = wid & 1;
    const int rowBase0 = by * 128;
    const int colBase0 = bx * 128;
    const int lr32 = lane & 31;   // row (A) / col (B) within 32-fragment
    const int kh = lane >> 5;     // k-half (8 contiguous k each)
    const int swz = (lr32 & 7) << 4;   // row-swizzle (rows are +0/+32/+64: &7 invariant)

    f32x16 acc[2][2];
    #pragma unroll
    for (int m = 0; m < 2; ++m)
        #pragma unroll
        for (int n = 0; n < 2; ++n)
            #pragma unroll
            for (int r = 0; r < 16; ++r) acc[m][n][r] = 0.f;

    #pragma unroll
    for (int kk = 0; kk < 8; ++kk) {
        const int cb = (kk * 32 + kh * 16) ^ swz;   // swizzled byte col
        bf16x8 a[2], b[2];
        #pragma unroll
        for (int m = 0; m < 2; ++m) {
            const int r = wr * 64 + m * 32 + lr32;
            a[m] = *(const bf16x8*)((const char*)lA + r * 256 + cb);
        }
        #pragma unroll
        for (int n = 0; n < 2; ++n) {
            const int r = wc * 64 + n * 32 + lr32;
            b[n] = *(const bf16x8*)((const char*)lB + r * 256 + cb);
        }
        #pragma unroll
        for (int m = 0; m < 2; ++m)
            #pragma unroll
            for (int n = 0; n < 2; ++n)
                acc[m][n] = __builtin_amdgcn_mfma_f32_32x32x16_bf16(a[m], b[n], acc[m][n], 0, 0, 0);
    }

    // exp + reductions. acc = x*2/ln2 (operands pre-scaled): bare v_exp_f32.
    float colpart[2] = {0.f, 0.f};
    #pragma unroll
    for (int m = 0; m < 2; ++m) {
        float rowpart[16];
        #pragma unroll
        for (int r = 0; r < 16; ++r) rowpart[r] = 0.f;
        #pragma unroll
        for (int n = 0; n < 2; ++n) {
            #pragma unroll
            for (int r = 0; r < 16; ++r) {
                float e = EXP2(acc[m][n][r]);
                rowpart[r] += e;
                colpart[n] += e;
            }
        }
        // multi-value fold: 16 regs over 32 lanes -> 1 reg (value = lane&15)
        float f[8], g[4], h[2], t;
        #pragma unroll
        for (int j = 0; j < 8; ++j) f[j] = fold2(rowpart[2*j], rowpart[2*j+1], 1, lane);
        #pragma unroll
        for (int j = 0; j < 4; ++j) g[j] = fold2(f[2*j], f[2*j+1], 2, lane);
        #pragma unroll
        for (int j = 0; j < 2; ++j) h[j] = fold2(g[2*j], g[2*j+1], 4, lane);
        t = fold2(h[0], h[1], 8, lane);
        t += __shfl_xor(t, 16);
        // lane l holds the full 32-col sum of reg r=l&15, i.e. row
        // (r&3)+8*((r>>2)&3)+4*kh of sub-tile m (duplicated at l^16).
        if ((lane & 16) == 0)
            atomicAdd(&rbuf[wr * 64 + m * 32 + (lane & 3) + 8 * ((lane >> 2) & 3) + 4 * kh], t);
    }
    if (needCols) {
        // col sums: lane l and l^32 hold the two row-halves of the same col
        #pragma unroll
        for (int n = 0; n < 2; ++n) {
            float s = colpart[n];
            s += __shfl_xor(s, 32);
            if (lane < 32) atomicAdd(&cbuf[wc * 64 + n * 32 + lr32], s);
        }
    }
    __syncthreads();

    if (tid < 128) {
        atomicAdd(rowS + rowBase0 + tid, rbuf[tid]);
        if (sym) {
            if (bx != by) atomicAdd(rowS + colBase0 + tid, cbuf[tid]);
        } else {
            atomicAdd(colS + colBase0 + tid, cbuf[tid]);
        }
    }
}

// ---------------------------------------------------------------------------
// fp32 diagonal of the between matrix: dAB[i] = A_i . B_i  (unit vectors).
// one wave per row, 4 rows per block.
// ---------------------------------------------------------------------------
__global__ __launch_bounds__(256) void diag_kernel(
    const float* __restrict__ Af, const float* __restrict__ Bf,
    float* __restrict__ dAB)
{
    const int wid = threadIdx.x >> 6, lane = threadIdx.x & 63;
    const int i = blockIdx.x * 4 + wid;
    float a0 = Af[(size_t)i * DIM + lane],      a1 = Af[(size_t)i * DIM + 64 + lane];
    float b0 = Bf[(size_t)i * DIM + lane],      b1 = Bf[(size_t)i * DIM + 64 + lane];
    float ab = a0 * b0 + a1 * b1;
    #pragma unroll
    for (int off = 32; off; off >>= 1) ab += __shfl_xor(ab, off);
    if (lane == 0) dAB[i] = ab;
}

// ---------------------------------------------------------------------------
// Final loss: mean over i of 0.5*(log den1 + log den2) - dAB/tau
//   den1 = S_AA[i] + S_AB[i] - e^2 ; den2 = S_BB[i] + S_BA[i] - e^2
// ---------------------------------------------------------------------------
__global__ __launch_bounds__(256) void loss_kernel(
    const float* __restrict__ sAA, const float* __restrict__ sAB,
    const float* __restrict__ sBA, const float* __restrict__ sBB,
    const float* __restrict__ dAB, float* __restrict__ out)
{
    __shared__ double part[256];
    double s = 0.0;
    for (int i = threadIdx.x; i < NROWS; i += 256) {
        float den1 = sAA[i] + sAB[i] - E2;
        float den2 = sBB[i] + sBA[i] - E2;
        s += 0.5 * ((double)logf(den1) + (double)logf(den2)) - (double)dAB[i] * 2.0;
    }
    part[threadIdx.x] = s;
    __syncthreads();
    for (int off = 128; off; off >>= 1) {
        if (threadIdx.x < off) part[threadIdx.x] += part[threadIdx.x + off];
        __syncthreads();
    }
    if (threadIdx.x == 0) out[0] = (float)(part[0] / NROWS);
}

// ---------------------------------------------------------------------------
extern "C" void kernel_launch(void* const* d_in, const int* in_sizes, int n_in,
                              void* d_out, int out_size, void* d_ws, size_t ws_size,
                              hipStream_t stream) {
    const float* z1 = (const float*)d_in[0];
    const float* z2 = (const float*)d_in[1];
    const float* W1 = (const float*)d_in[2];
    const float* b1 = (const float*)d_in[3];
    const float* W2 = (const float*)d_in[4];
    const float* b2 = (const float*)d_in[5];
    float* out = (float*)d_out;

    char* w = (char*)d_ws;
    float* Af = (float*)w;                 w += (size_t)NROWS * DIM * sizeof(float);
    float* Bf = (float*)w;                 w += (size_t)NROWS * DIM * sizeof(float);
    __hip_bfloat16* Ab = (__hip_bfloat16*)w; w += (size_t)NROWS * DIM * sizeof(__hip_bfloat16);
    __hip_bfloat16* Bb = (__hip_bfloat16*)w; w += (size_t)NROWS * DIM * sizeof(__hip_bfloat16);
    float* S_AA = (float*)w;               w += NROWS * sizeof(float);
    float* S_AB = (float*)w;               w += NROWS * sizeof(float);
    float* S_BA = (float*)w;               w += NROWS * sizeof(float);
    float* S_BB = (float*)w;               w += NROWS * sizeof(float);
    float* dAB  = (float*)w;               w += NROWS * sizeof(float);

    // zero the four accumulator arrays (contiguous)
    hipMemsetAsync(S_AA, 0, 4 * NROWS * sizeof(float), stream);

    proj_kernel<<<2 * (NROWS / 16), 128, 0, stream>>>(
        z1, z2, W1, b1, W2, b2, Af, Bf, Ab, Bb);

    pairsum_all_kernel<<<TOTAL_BLOCKS, 256, 0, stream>>>(
        (const short*)Ab, (const short*)Bb, S_AA, S_AB, S_BA, S_BB);

    diag_kernel<<<NROWS / 4, 256, 0, stream>>>(Af, Bf, dAB);
    loss_kernel<<<1, 256, 0, stream>>>(S_AA, S_AB, S_BA, S_BB, dAB, out);
}

// Round 13
// 389.586 us; speedup vs baseline: 1.6939x; 1.2673x over previous
//
#include <hip/hip_runtime.h>
#include <hip/hip_bf16.h>
#include <math.h>

typedef __attribute__((ext_vector_type(8))) short bf16x8;
typedef __attribute__((ext_vector_type(16))) float f32x16;

#define NROWS 16384
#define DIM 128
#define NB 128                   // 128x128 tiles per dim
#define TRI (NB * (NB + 1) / 2)  // 8256 triangular blocks
#define TOTAL_BLOCKS (2 * TRI + NB * NB)  // 32896, divisible by 8

// Ab entries are pre-scaled by sqrt(2/ln2) so that the bf16 Gram dot equals
// x * 2/ln2, i.e. exp(x/tau) = exp2(dot) with no epilogue multiply.
#define OP_SCALE 1.69864360057604f
// exp(1/tau) = exp(2): the refl diagonal (an.an == 1 exactly)
#define E2 7.38905609893065f

// raw v_exp_f32 when available (args provably in [-3,3]; no guards needed)
#if __has_builtin(__builtin_amdgcn_exp2f)
#define EXP2(x) __builtin_amdgcn_exp2f(x)
#else
#define EXP2(x) __expf((x) * 0.6931471805599453f)
#endif
#define LOG2E 1.44269504088896f

// ---------------------------------------------------------------------------
// Projection: h = elu(z@W1+b1)@W2+b2 ; A = h/max(||h||,eps). fp32 throughout.
// Emits fp32 copy (for exact diag) and pre-scaled bf16 copy (for MFMA).
// Both z1 and z2 in ONE launch. Block = 128 threads, 16 rows per block.
// ---------------------------------------------------------------------------
__global__ __launch_bounds__(128) void proj_kernel(
    const float* __restrict__ z1, const float* __restrict__ z2,
    const float* __restrict__ W1, const float* __restrict__ b1,
    const float* __restrict__ W2, const float* __restrict__ b2,
    float* __restrict__ Af, float* __restrict__ Bf,
    __hip_bfloat16* __restrict__ Ab, __hip_bfloat16* __restrict__ Bb)
{
    const int ROWS = 16;
    const int HALF = NROWS / ROWS;         // 1024 blocks per input
    __shared__ float zs[ROWS][DIM];
    __shared__ float es[ROWS][DIM];
    __shared__ float wavesum[2][ROWS];
    __shared__ float scale[ROWS];

    const int tid = threadIdx.x;           // 0..127 (owns one output column)
    const bool second = blockIdx.x >= HALF;
    const float* z = second ? z2 : z1;
    float* Xf = second ? Bf : Af;
    __hip_bfloat16* Xb = second ? Bb : Ab;
    const int row0 = (second ? blockIdx.x - HALF : blockIdx.x) * ROWS;

    #pragma unroll
    for (int r = 0; r < ROWS; ++r)
        zs[r][tid] = z[(row0 + r) * DIM + tid];
    __syncthreads();

    float acc[ROWS];
    #pragma unroll
    for (int r = 0; r < ROWS; ++r) acc[r] = 0.f;
    for (int k = 0; k < DIM; ++k) {
        float w = W1[k * DIM + tid];
        #pragma unroll
        for (int r = 0; r < ROWS; ++r) acc[r] = fmaf(zs[r][k], w, acc[r]);
    }
    float bb1 = b1[tid];
    #pragma unroll
    for (int r = 0; r < ROWS; ++r) {
        float t = acc[r] + bb1;
        // elu: exp(t)-1 via raw v_exp_f32 (abs err ~1e-7, fine for the dot)
        es[r][tid] = t > 0.f ? t : (EXP2(t * LOG2E) - 1.f);
    }
    __syncthreads();

    #pragma unroll
    for (int r = 0; r < ROWS; ++r) acc[r] = 0.f;
    for (int h = 0; h < DIM; ++h) {
        float w = W2[h * DIM + tid];
        #pragma unroll
        for (int r = 0; r < ROWS; ++r) acc[r] = fmaf(es[r][h], w, acc[r]);
    }
    float bb2 = b2[tid];
    #pragma unroll
    for (int r = 0; r < ROWS; ++r) acc[r] += bb2;

    // per-row L2 norms: shuffle-reduce within each of the 2 waves, combine in LDS
    const int wave = tid >> 6, lane = tid & 63;
    #pragma unroll
    for (int r = 0; r < ROWS; ++r) {
        float s = acc[r] * acc[r];
        #pragma unroll
        for (int off = 32; off; off >>= 1) s += __shfl_xor(s, off);
        if (lane == 0) wavesum[wave][r] = s;
    }
    __syncthreads();
    if (tid < ROWS) {
        float n = sqrtf(wavesum[0][tid] + wavesum[1][tid]);
        scale[tid] = 1.f / fmaxf(n, 1e-12f);
    }
    __syncthreads();

    #pragma unroll
    for (int r = 0; r < ROWS; ++r) {
        float a = acc[r] * scale[r];
        Xf[(row0 + r) * DIM + tid] = a;
        Xb[(row0 + r) * DIM + tid] = __float2bfloat16(a * OP_SCALE);
    }
}

// ---------------------------------------------------------------------------
// Select-exchange fold: combine two per-lane partial sets a,b over xor-pairs d.
// ---------------------------------------------------------------------------
__device__ __forceinline__ float fold2(float a, float b, int d, int lane) {
    float x = (lane & d) ? b : a;
    float y = (lane & d) ? a : b;
    return x + __shfl_xor(y, d);
}

// ---------------------------------------------------------------------------
// Fused pairwise exp-Gram sums, single 1D grid covering all three products:
//   region 0: AA (symmetric, triangular blocks bx<=by), rowS = S_AA
//   region 1: AB (full grid, L2-supertiled 8by x 16bx), rowS=S_AB, colS=S_BA
//   region 2: BB (symmetric, triangular), rowS = S_BB
// 256 threads = 4 waves, 1x4 split: wave w owns rows [w*32,w*32+32) x all
// 128 cols. A-fragments global->reg ONCE (8 b128, register-resident, 4x
// in-register reuse); only B staged to LDS (32 KB -> 4 blocks/CU).
// Swizzle byte^=((row&15)<<4) on write AND read (involution): 32 rows at one
// column map to 16 distinct 16B slots -> 2-way bank aliasing (free, m136).
// Inner product: mfma_f32_32x32x16_bf16, 1x4 of 32x32 per wave, 8 K-steps.
// C/D: col=lane&31, row=(reg&3)+8*(reg>>2)+4*(lane>>5) [m74/m101-verified].
// Row sums: one 4-step multi-value butterfly fold per wave + shfl_xor(16),
// then one 32-lane global atomic (waves own disjoint row ranges -> no rbuf).
// Col sums still combine across waves via cbuf LDS atomics.
// ---------------------------------------------------------------------------
__global__ __launch_bounds__(256, 4) void pairsum_all_kernel(
    const short* __restrict__ Ab, const short* __restrict__ Bb,
    float* __restrict__ S_AA, float* __restrict__ S_AB,
    float* __restrict__ S_BA, float* __restrict__ S_BB)
{
    // bijective XCD swizzle: 32896 = 8 * 4112
    const int bid0 = blockIdx.x;
    const int t0 = (bid0 & 7) * (TOTAL_BLOCKS / 8) + (bid0 >> 3);

    const short* A;
    const short* B;
    float* rowS;
    float* colS = nullptr;
    int bx, by, sym;

    if (t0 < TRI) {                       // AA triangular
        int t = t0;
        by = (int)((sqrtf(8.0f * t + 1.0f) - 1.0f) * 0.5f);
        while ((by + 1) * (by + 2) / 2 <= t) ++by;
        while (by * (by + 1) / 2 > t) --by;
        bx = t - by * (by + 1) / 2;
        A = Ab; B = Ab; rowS = S_AA; sym = 1;
    } else if (t0 < TRI + NB * NB) {      // AB full, supertiled for L2
        int t = t0 - TRI;
        // supertile: 8 by-panels x 16 bx-panels = 768 KB working set << 4MB L2
        int st = t >> 7, win = t & 127;
        int stx = st & 7, sty = st >> 3;
        bx = stx * 16 + (win & 15);
        by = sty * 8 + (win >> 4);
        A = Ab; B = Bb; rowS = S_AB; colS = S_BA; sym = 0;
    } else {                              // BB triangular
        int t = t0 - TRI - NB * NB;
        by = (int)((sqrtf(8.0f * t + 1.0f) - 1.0f) * 0.5f);
        while ((by + 1) * (by + 2) / 2 <= t) ++by;
        while (by * (by + 1) / 2 > t) --by;
        bx = t - by * (by + 1) / 2;
        A = Bb; B = Bb; rowS = S_BB; sym = 1;
    }
    const bool needCols = !sym || (bx != by);

    __shared__ __align__(16) short lB[NB * DIM];   // 32 KB, swizzled 256B rows
    __shared__ float cbuf[128];
    const int tid = threadIdx.x;
    if (tid < 128) cbuf[tid] = 0.f;

    const int wid = tid >> 6, lane = tid & 63;
    const int lr32 = lane & 31;   // A-row / B-col within 32-fragment
    const int kh = lane >> 5;     // k-half (8 contiguous k each)

    // ---- A fragments: wave wid owns rows [wid*32, wid*32+32); reg-resident.
    bf16x8 af[8];
    {
        const short* gA = A + (size_t)(by * 128 + wid * 32 + lr32) * DIM + kh * 8;
        #pragma unroll
        for (int kk = 0; kk < 8; ++kk)
            af[kk] = *(const bf16x8*)(gA + kk * 16);
    }

    // ---- stage B: 32KB contiguous slab, 8 x 16B units per thread
    {
        const short* gB = B + (size_t)bx * 128 * DIM;
        bf16x8 bv[8];
        #pragma unroll
        for (int i = 0; i < 8; ++i) {
            const int unit = i * 256 + tid;        // 16B unit index 0..2047
            bv[i] = *(const bf16x8*)(gB + unit * 8);
        }
        #pragma unroll
        for (int i = 0; i < 8; ++i) {
            const int unit = i * 256 + tid;
            const int row = unit >> 4;             // local row 0..127
            const int dst = row * 256 + (((unit & 15) * 16) ^ ((row & 15) << 4));
            *(bf16x8*)((char*)lB + dst) = bv[i];
        }
    }
    __syncthreads();

    const int swz = (lr32 & 15) << 4;   // read swizzle (row = n*32+lr32; &15 invariant)

    f32x16 acc[4];
    #pragma unroll
    for (int n = 0; n < 4; ++n)
        #pragma unroll
        for (int r = 0; r < 16; ++r) acc[n][r] = 0.f;

    #pragma unroll
    for (int kk = 0; kk < 8; ++kk) {
        const int cb = (kk * 32 + kh * 16) ^ swz;   // swizzled byte col
        bf16x8 b[4];
        #pragma unroll
        for (int n = 0; n < 4; ++n)
            b[n] = *(const bf16x8*)((const char*)lB + (n * 32 + lr32) * 256 + cb);
        #pragma unroll
        for (int n = 0; n < 4; ++n)
            acc[n] = __builtin_amdgcn_mfma_f32_32x32x16_bf16(af[kk], b[n], acc[n], 0, 0, 0);
    }

    // exp + reductions. acc = x*2/ln2 (operands pre-scaled): bare v_exp_f32.
    float colpart[4] = {0.f, 0.f, 0.f, 0.f};
    float rowpart[16];
    #pragma unroll
    for (int r = 0; r < 16; ++r) rowpart[r] = 0.f;
    #pragma unroll
    for (int n = 0; n < 4; ++n) {
        #pragma unroll
        for (int r = 0; r < 16; ++r) {
            float e = EXP2(acc[n][r]);
            rowpart[r] += e;
            colpart[n] += e;
        }
    }
    // multi-value fold: 16 regs over 32 lanes -> 1 reg (value = lane&15)
    {
        float f[8], g[4], h[2], t;
        #pragma unroll
        for (int j = 0; j < 8; ++j) f[j] = fold2(rowpart[2*j], rowpart[2*j+1], 1, lane);
        #pragma unroll
        for (int j = 0; j < 4; ++j) g[j] = fold2(f[2*j], f[2*j+1], 2, lane);
        #pragma unroll
        for (int j = 0; j < 2; ++j) h[j] = fold2(g[2*j], g[2*j+1], 4, lane);
        t = fold2(h[0], h[1], 8, lane);
        t += __shfl_xor(t, 16);
        // lanes 0-15 (kh=0) and 32-47 (kh=1) hold the 32 distinct row sums
        if ((lane & 16) == 0)
            atomicAdd(rowS + by * 128 + wid * 32 +
                      (lane & 3) + 8 * ((lane >> 2) & 3) + 4 * kh, t);
    }
    if (needCols) {
        // col sums: lane l and l^32 hold the two kh row-halves of the same col
        #pragma unroll
        for (int n = 0; n < 4; ++n) {
            float s = colpart[n];
            s += __shfl_xor(s, 32);
            if (lane < 32) atomicAdd(&cbuf[n * 32 + lr32], s);
        }
        __syncthreads();
        if (tid < 128) {
            if (sym) atomicAdd(rowS + bx * 128 + tid, cbuf[tid]);
            else     atomicAdd(colS + bx * 128 + tid, cbuf[tid]);
        }
    }
}

// ---------------------------------------------------------------------------
// fp32 diagonal of the between matrix: dAB[i] = A_i . B_i  (unit vectors).
// one wave per row, 4 rows per block.
// ---------------------------------------------------------------------------
__global__ __launch_bounds__(256) void diag_kernel(
    const float* __restrict__ Af, const float* __restrict__ Bf,
    float* __restrict__ dAB)
{
    const int wid = threadIdx.x >> 6, lane = threadIdx.x & 63;
    const int i = blockIdx.x * 4 + wid;
    float a0 = Af[(size_t)i * DIM + lane],      a1 = Af[(size_t)i * DIM + 64 + lane];
    float b0 = Bf[(size_t)i * DIM + lane],      b1 = Bf[(size_t)i * DIM + 64 + lane];
    float ab = a0 * b0 + a1 * b1;
    #pragma unroll
    for (int off = 32; off; off >>= 1) ab += __shfl_xor(ab, off);
    if (lane == 0) dAB[i] = ab;
}

// ---------------------------------------------------------------------------
// Final loss: mean over i of 0.5*(log den1 + log den2) - dAB/tau
//   den1 = S_AA[i] + S_AB[i] - e^2 ; den2 = S_BB[i] + S_BA[i] - e^2
// ---------------------------------------------------------------------------
__global__ __launch_bounds__(256) void loss_kernel(
    const float* __restrict__ sAA, const float* __restrict__ sAB,
    const float* __restrict__ sBA, const float* __restrict__ sBB,
    const float* __restrict__ dAB, float* __restrict__ out)
{
    __shared__ double part[256];
    double s = 0.0;
    for (int i = threadIdx.x; i < NROWS; i += 256) {
        float den1 = sAA[i] + sAB[i] - E2;
        float den2 = sBB[i] + sBA[i] - E2;
        s += 0.5 * ((double)logf(den1) + (double)logf(den2)) - (double)dAB[i] * 2.0;
    }
    part[threadIdx.x] = s;
    __syncthreads();
    for (int off = 128; off; off >>= 1) {
        if (threadIdx.x < off) part[threadIdx.x] += part[threadIdx.x + off];
        __syncthreads();
    }
    if (threadIdx.x == 0) out[0] = (float)(part[0] / NROWS);
}

// ---------------------------------------------------------------------------
extern "C" void kernel_launch(void* const* d_in, const int* in_sizes, int n_in,
                              void* d_out, int out_size, void* d_ws, size_t ws_size,
                              hipStream_t stream) {
    const float* z1 = (const float*)d_in[0];
    const float* z2 = (const float*)d_in[1];
    const float* W1 = (const float*)d_in[2];
    const float* b1 = (const float*)d_in[3];
    const float* W2 = (const float*)d_in[4];
    const float* b2 = (const float*)d_in[5];
    float* out = (float*)d_out;

    char* w = (char*)d_ws;
    float* Af = (float*)w;                 w += (size_t)NROWS * DIM * sizeof(float);
    float* Bf = (float*)w;                 w += (size_t)NROWS * DIM * sizeof(float);
    __hip_bfloat16* Ab = (__hip_bfloat16*)w; w += (size_t)NROWS * DIM * sizeof(__hip_bfloat16);
    __hip_bfloat16* Bb = (__hip_bfloat16*)w; w += (size_t)NROWS * DIM * sizeof(__hip_bfloat16);
    float* S_AA = (float*)w;               w += NROWS * sizeof(float);
    float* S_AB = (float*)w;               w += NROWS * sizeof(float);
    float* S_BA = (float*)w;               w += NROWS * sizeof(float);
    float* S_BB = (float*)w;               w += NROWS * sizeof(float);
    float* dAB  = (float*)w;               w += NROWS * sizeof(float);

    // zero the four accumulator arrays (contiguous)
    hipMemsetAsync(S_AA, 0, 4 * NROWS * sizeof(float), stream);

    proj_kernel<<<2 * (NROWS / 16), 128, 0, stream>>>(
        z1, z2, W1, b1, W2, b2, Af, Bf, Ab, Bb);

    pairsum_all_kernel<<<TOTAL_BLOCKS, 256, 0, stream>>>(
        (const short*)Ab, (const short*)Bb, S_AA, S_AB, S_BA, S_BB);

    diag_kernel<<<NROWS / 4, 256, 0, stream>>>(Af, Bf, dAB);
    loss_kernel<<<1, 256, 0, stream>>>(S_AA, S_AB, S_BA, S_BB, dAB, out);
}